// Round 1
// 829.695 us; speedup vs baseline: 1.2078x; 1.2078x over previous
//
#include <hip/hip_runtime.h>
#include <math.h>

#define B_ 64
#define N_ 1025
#define D_ 1024
#define C_ 64
#define HW_ 1024

static constexpr float LN_EPS_F = 1e-5f;

typedef __attribute__((ext_vector_type(8))) short short8;   // 8 x bf16 (4 VGPRs)
typedef __attribute__((ext_vector_type(4))) float f32x4;    // MFMA accumulator
typedef __attribute__((ext_vector_type(2))) unsigned int uint2v;

// ---------------------------------------------------------------------------
// K1: fused LayerNorm + gamma/gammax scale + GEMM1 (D->C) via bf16 MFMA.
// grid 2050 (65600 rows / 32), block 256 (4 waves). 32 rows per block.
// Phase 1: each wave LNs 8 rows (shuffle reduce), packs to bf16
//          (v_cvt_pk_bf16_f32) and stores into XOR-swizzled LDS
//          (byte ^= (row&7)<<4  -- kills the 16-way conflict of the
//          2048B row stride on ds_read_b128, perfectly balanced).
// Phase 2: wave w owns output cols 16w..16w+15 for BOTH 16-row M-tiles.
//          A-frag: one ds_read_b128 per tile (lane&15 = row, lane>>4 = k-chunk,
//          8 ascending k per lane). B-frag: 8 strided L2-hot w1 loads packed
//          with the SAME k mapping -> layout is permutation-proof in k.
//          C/D: col = lane&15, row = (lane>>4)*4 + reg (measured layout).
// ---------------------------------------------------------------------------
__global__ __launch_bounds__(256) void k1_ln_gemm1(
    const float* __restrict__ x, const float* __restrict__ ln_w,
    const float* __restrict__ ln_b, const float* __restrict__ gamma,
    const float* __restrict__ gammax, const float* __restrict__ w1,
    const float* __restrict__ b1, float* __restrict__ y1)
{
    __shared__ ushort t2[32][1024];          // bf16, swizzled, 64 KB
    const int tid  = threadIdx.x;
    const int lane = tid & 63;
    const int wv   = tid >> 6;
    const int base = blockIdx.x * 32;

    // ---- hoist the per-d parameter vectors (same for every row) ----
    float4 lw[4], lb[4], gm[4], gx[4];
    #pragma unroll
    for (int q = 0; q < 4; ++q) {
        const int d = q * 256 + lane * 4;
        lw[q] = *(const float4*)(ln_w   + d);
        lb[q] = *(const float4*)(ln_b   + d);
        gm[q] = *(const float4*)(gamma  + d);
        gx[q] = *(const float4*)(gammax + d);
    }

    // ---- Phase 1: LayerNorm + scale + bf16 pack, 8 rows per wave ----
    for (int j = 0; j < 8; ++j) {
        const int i = wv * 8 + j;
        const int r = base + i;              // global row in [0, 65600)
        const int b = r / N_;
        const int n = r - b * N_;
        const float* xrow = x + (size_t)n * (B_ * D_) + (size_t)b * D_;

        float4 v[4];
        float s = 0.f, sq = 0.f;
        #pragma unroll
        for (int q = 0; q < 4; ++q) {
            v[q] = *(const float4*)(xrow + q * 256 + lane * 4);
            s  += v[q].x + v[q].y + v[q].z + v[q].w;
            sq += v[q].x * v[q].x + v[q].y * v[q].y
                + v[q].z * v[q].z + v[q].w * v[q].w;
        }
        #pragma unroll
        for (int off = 32; off > 0; off >>= 1) {
            s  += __shfl_xor(s,  off, 64);
            sq += __shfl_xor(sq, off, 64);
        }
        const float mu  = s * (1.0f / D_);
        const float var = sq * (1.0f / D_) - mu * mu;
        const float rs  = rsqrtf(var + LN_EPS_F);

        char* trow = (char*)&t2[i][0];
        const int sw = (i & 7) << 4;
        #pragma unroll
        for (int q = 0; q < 4; ++q) {
            float4 o;
            o.x = ((v[q].x - mu) * rs * lw[q].x + lb[q].x) * gm[q].x + v[q].x * gx[q].x;
            o.y = ((v[q].y - mu) * rs * lw[q].y + lb[q].y) * gm[q].y + v[q].y * gx[q].y;
            o.z = ((v[q].z - mu) * rs * lw[q].z + lb[q].z) * gm[q].z + v[q].z * gx[q].z;
            o.w = ((v[q].w - mu) * rs * lw[q].w + lb[q].w) * gm[q].w + v[q].w * gx[q].w;
            unsigned int p01, p23;
            asm("v_cvt_pk_bf16_f32 %0, %1, %2" : "=v"(p01) : "v"(o.x), "v"(o.y));
            asm("v_cvt_pk_bf16_f32 %0, %1, %2" : "=v"(p23) : "v"(o.z), "v"(o.w));
            uint2v pv; pv.x = p01; pv.y = p23;
            *(uint2v*)(trow + ((q * 512 + lane * 8) ^ sw)) = pv;   // 8B, swizzled
        }
    }
    __syncthreads();

    // ---- Phase 2: MFMA GEMM (32 rows x 64 cols), 2 M-tiles per wave ----
    const int lo16 = lane & 15;
    const int hi4  = lane >> 4;
    const int ccol = wv * 16 + lo16;                 // output col 0..63
    const char* t2b  = (const char*)t2;
    const int  roff0 = lo16 * 2048;                  // M-tile 0 row base (bytes)
    const int  roff1 = roff0 + 16 * 2048;            // M-tile 1
    const int  sw2   = (lo16 & 7) << 4;              // (16+lo16)&7 == lo16&7
    const int  hoff  = hi4 * 16;                     // k-chunk byte offset
    const float* w1p = w1 + (size_t)(hi4 * 8) * C_ + ccol;

    f32x4 acc0 = {0.f, 0.f, 0.f, 0.f};
    f32x4 acc1 = {0.f, 0.f, 0.f, 0.f};

    #pragma unroll 4
    for (int kb = 0; kb < D_; kb += 32) {
        const int off = (kb * 2 + hoff) ^ sw2;
        short8 a0 = *(const short8*)(t2b + roff0 + off);
        short8 a1 = *(const short8*)(t2b + roff1 + off);

        const float* wp = w1p + kb * C_;
        const float w0 = wp[0 * C_], w1v = wp[1 * C_];
        const float w2v = wp[2 * C_], w3v = wp[3 * C_];
        const float w4v = wp[4 * C_], w5v = wp[5 * C_];
        const float w6v = wp[6 * C_], w7v = wp[7 * C_];
        unsigned int p0, p1, p2, p3;
        asm("v_cvt_pk_bf16_f32 %0, %1, %2" : "=v"(p0) : "v"(w0),  "v"(w1v));
        asm("v_cvt_pk_bf16_f32 %0, %1, %2" : "=v"(p1) : "v"(w2v), "v"(w3v));
        asm("v_cvt_pk_bf16_f32 %0, %1, %2" : "=v"(p2) : "v"(w4v), "v"(w5v));
        asm("v_cvt_pk_bf16_f32 %0, %1, %2" : "=v"(p3) : "v"(w6v), "v"(w7v));
        union { unsigned int u[4]; short8 s; } bu;
        bu.u[0] = p0; bu.u[1] = p1; bu.u[2] = p2; bu.u[3] = p3;

        acc0 = __builtin_amdgcn_mfma_f32_16x16x32_bf16(a0, bu.s, acc0, 0, 0, 0);
        acc1 = __builtin_amdgcn_mfma_f32_16x16x32_bf16(a1, bu.s, acc1, 0, 0, 0);
    }

    const float bb   = b1[ccol];
    const int   row0 = base + hi4 * 4;
    #pragma unroll
    for (int g2 = 0; g2 < 4; ++g2) {
        y1[(size_t)(row0 + g2)      * C_ + ccol] = acc0[g2] + bb;
        y1[(size_t)(row0 + 16 + g2) * C_ + ccol] = acc1[g2] + bb;
    }
}

// ---------------------------------------------------------------------------
// K2: depthwise conv. The 3 convs are linear -> fold into ONE 7x7 kernel:
//     K7 = (dw7 + pad(dw5) + pad(dw3)) / 3, bias = (b3+b5+b7)/3.
// Output: sp2[b][c][p] = conv7(img)[p] + img[p]  (identity residual).
// grid 4096 (B*C), block 256; one 32x32 image per block in LDS.
// ---------------------------------------------------------------------------
__global__ __launch_bounds__(256) void k2_dwconv(
    const float* __restrict__ y1,
    const float* __restrict__ dw3_w, const float* __restrict__ dw3_b,
    const float* __restrict__ dw5_w, const float* __restrict__ dw5_b,
    const float* __restrict__ dw7_w, const float* __restrict__ dw7_b,
    float* __restrict__ sp2)
{
    __shared__ float img[HW_];
    __shared__ float k7[49];
    const int b   = blockIdx.x >> 6;
    const int c   = blockIdx.x & 63;
    const int tid = threadIdx.x;

    #pragma unroll
    for (int q = 0; q < 4; ++q) {
        const int p = tid + q * 256;
        img[p] = y1[(size_t)(b * N_ + 1 + p) * C_ + c];
    }
    if (tid < 49) {
        const int di = tid / 7, dj = tid % 7;
        float v = dw7_w[c * 49 + tid];
        if (di >= 1 && di <= 5 && dj >= 1 && dj <= 5)
            v += dw5_w[c * 25 + (di - 1) * 5 + (dj - 1)];
        if (di >= 2 && di <= 4 && dj >= 2 && dj <= 4)
            v += dw3_w[c * 9 + (di - 2) * 3 + (dj - 2)];
        k7[tid] = v * (1.0f / 3.0f);
    }
    __syncthreads();

    const float bias = (dw3_b[c] + dw5_b[c] + dw7_b[c]) * (1.0f / 3.0f);
    #pragma unroll
    for (int q = 0; q < 4; ++q) {
        const int p = tid + q * 256;
        const int i = p >> 5, j0 = p & 31;
        float acc = bias;
        #pragma unroll
        for (int ki = 0; ki < 7; ++ki) {
            const int ii = i + ki - 3;
            if ((unsigned)ii < 32u) {
                #pragma unroll
                for (int kj = 0; kj < 7; ++kj) {
                    const int jj = j0 + kj - 3;
                    if ((unsigned)jj < 32u)
                        acc += img[ii * 32 + jj] * k7[ki * 7 + kj];
                }
            }
        }
        sp2[(size_t)blockIdx.x * HW_ + p] = acc + img[p];
    }
}

// ---------------------------------------------------------------------------
// K3: 1x1 proj (C x C matvec) + residual + exact GELU + repack to (B,N,C).
// One wave per row; lane = output channel. The row vector is staged in LDS
// and read back as wave-uniform float4 broadcasts (replaces 64 ds_bpermute
// per row with 16 broadcast ds_read_b128). proj_w rows live in L1 (16 KB).
// grid 16400 (65600/4), block 256.
// ---------------------------------------------------------------------------
__global__ __launch_bounds__(256) void k3_proj_gelu(
    const float* __restrict__ y1, const float* __restrict__ sp2,
    const float* __restrict__ proj_w, const float* __restrict__ proj_b,
    float* __restrict__ g)
{
    __shared__ float gs[4][C_];
    const int tid  = threadIdx.x;
    const int lane = tid & 63;
    const int wv   = tid >> 6;
    const int r = blockIdx.x * 4 + wv;   // row in [0, 65600)
    const int b = r / N_;
    const int n = r - b * N_;

    float v;
    if (n == 0)
        v = y1[(size_t)r * C_ + lane];
    else
        v = sp2[((size_t)b * C_ + lane) * HW_ + (n - 1)];
    gs[wv][lane] = v;
    __syncthreads();

    float acc = proj_b[lane];
    const float* pw = proj_w + lane * C_;
    #pragma unroll
    for (int cc = 0; cc < C_; cc += 4) {
        const float4 pv = *(const float4*)(pw + cc);
        const float4 vv = *(const float4*)&gs[wv][cc];   // wave-uniform: broadcast
        acc += pv.x * vv.x + pv.y * vv.y + pv.z * vv.z + pv.w * vv.w;
    }

    const float o  = (n == 0) ? v : (v + acc);
    const float ge = 0.5f * o * (1.0f + erff(o * 0.70710678118654752f));
    g[(size_t)r * C_ + lane] = ge;
}

// ---------------------------------------------------------------------------
// K4: GEMM2 (C->D) + b2 + identity residual + transpose to (N,B,D).
// grid 4100, block 256; 16 rows per block. g rows staged in LDS (4 KB);
// w2 read as float4 (coalesced 1KB/instr, L2-hot, ~1 GB total);
// x read / out write coalesced float4.
// ---------------------------------------------------------------------------
__global__ __launch_bounds__(256) void k4_gemm2(
    const float* __restrict__ g, const float* __restrict__ w2,
    const float* __restrict__ b2, const float* __restrict__ x,
    float* __restrict__ out)
{
    __shared__ float gs[16][C_];
    const int tid  = threadIdx.x;
    const int base = blockIdx.x * 16;

    ((float4*)&gs[0][0])[tid] = *(const float4*)(g + (size_t)base * C_ + tid * 4);
    __syncthreads();

    const int d = tid * 4;
    float4 acc[16];
    #pragma unroll
    for (int i = 0; i < 16; ++i) acc[i] = make_float4(0.f, 0.f, 0.f, 0.f);

    for (int cb = 0; cb < C_; cb += 4) {
        float4 w0 = *(const float4*)(w2 + (size_t)(cb + 0) * D_ + d);
        float4 w1v = *(const float4*)(w2 + (size_t)(cb + 1) * D_ + d);
        float4 w2v = *(const float4*)(w2 + (size_t)(cb + 2) * D_ + d);
        float4 w3v = *(const float4*)(w2 + (size_t)(cb + 3) * D_ + d);
        #pragma unroll
        for (int i = 0; i < 16; ++i) {
            float4 gv = *(const float4*)&gs[i][cb];   // wave-uniform: broadcast
            acc[i].x += gv.x * w0.x + gv.y * w1v.x + gv.z * w2v.x + gv.w * w3v.x;
            acc[i].y += gv.x * w0.y + gv.y * w1v.y + gv.z * w2v.y + gv.w * w3v.y;
            acc[i].z += gv.x * w0.z + gv.y * w1v.z + gv.z * w2v.z + gv.w * w3v.z;
            acc[i].w += gv.x * w0.w + gv.y * w1v.w + gv.z * w2v.w + gv.w * w3v.w;
        }
    }

    const float4 bv = *(const float4*)(b2 + d);
    #pragma unroll
    for (int i = 0; i < 16; ++i) {
        const int r = base + i;
        const int b = r / N_;
        const int n = r - b * N_;
        const size_t idx = (size_t)n * (B_ * D_) + (size_t)b * D_ + d;
        float4 xv = *(const float4*)(x + idx);
        float4 o;
        o.x = xv.x + acc[i].x + bv.x;
        o.y = xv.y + acc[i].y + bv.y;
        o.z = xv.z + acc[i].z + bv.z;
        o.w = xv.w + acc[i].w + bv.w;
        *(float4*)(out + idx) = o;
    }
}

// ---------------------------------------------------------------------------
extern "C" void kernel_launch(void* const* d_in, const int* in_sizes, int n_in,
                              void* d_out, int out_size, void* d_ws, size_t ws_size,
                              hipStream_t stream)
{
    const float* x      = (const float*)d_in[0];
    const float* ln_w   = (const float*)d_in[1];
    const float* ln_b   = (const float*)d_in[2];
    const float* gamma  = (const float*)d_in[3];
    const float* gammax = (const float*)d_in[4];
    const float* w1     = (const float*)d_in[5];
    const float* b1     = (const float*)d_in[6];
    const float* w2     = (const float*)d_in[7];
    const float* b2     = (const float*)d_in[8];
    const float* dw3_w  = (const float*)d_in[9];
    const float* dw3_b  = (const float*)d_in[10];
    const float* dw5_w  = (const float*)d_in[11];
    const float* dw5_b  = (const float*)d_in[12];
    const float* dw7_w  = (const float*)d_in[13];
    const float* dw7_b  = (const float*)d_in[14];
    const float* proj_w = (const float*)d_in[15];
    const float* proj_b = (const float*)d_in[16];
    float* out = (float*)d_out;

    // workspace: y1 (B*N*C) | sp2 (B*C*HW) | g (B*N*C)  ~= 50.4 MB
    float* y1  = (float*)d_ws;
    float* sp2 = y1 + (size_t)B_ * N_ * C_;
    float* gbf = sp2 + (size_t)B_ * C_ * HW_;

    k1_ln_gemm1<<<2050, 256, 0, stream>>>(x, ln_w, ln_b, gamma, gammax, w1, b1, y1);
    k2_dwconv<<<4096, 256, 0, stream>>>(y1, dw3_w, dw3_b, dw5_w, dw5_b,
                                        dw7_w, dw7_b, sp2);
    k3_proj_gelu<<<16400, 256, 0, stream>>>(y1, sp2, proj_w, proj_b, gbf);
    k4_gemm2<<<4100, 256, 0, stream>>>(gbf, w2, b2, x, out);
}

// Round 2
// 654.790 us; speedup vs baseline: 1.5304x; 1.2671x over previous
//
#include <hip/hip_runtime.h>
#include <math.h>

#define B_ 64
#define N_ 1025
#define D_ 1024
#define C_ 64
#define HW_ 1024

static constexpr float LN_EPS_F = 1e-5f;

typedef __attribute__((ext_vector_type(8))) short short8;   // 8 x bf16 (4 VGPRs)
typedef __attribute__((ext_vector_type(4))) float f32x4;    // MFMA accumulator
typedef __attribute__((ext_vector_type(2))) unsigned int uint2v;

__device__ __forceinline__ short8 pack8(float a0, float a1, float a2, float a3,
                                        float a4, float a5, float a6, float a7)
{
    union { unsigned u[4]; short8 s; } r;
    asm("v_cvt_pk_bf16_f32 %0, %1, %2" : "=v"(r.u[0]) : "v"(a0), "v"(a1));
    asm("v_cvt_pk_bf16_f32 %0, %1, %2" : "=v"(r.u[1]) : "v"(a2), "v"(a3));
    asm("v_cvt_pk_bf16_f32 %0, %1, %2" : "=v"(r.u[2]) : "v"(a4), "v"(a5));
    asm("v_cvt_pk_bf16_f32 %0, %1, %2" : "=v"(r.u[3]) : "v"(a6), "v"(a7));
    return r.s;
}

// ---------------------------------------------------------------------------
// K0: pre-pack w1 (1024x64) and w2 (64x1024) into bf16 MFMA B-fragment order:
//   w1s[((nt*32+kb)*64+lane)*8+e] = bf16(w1[(kb*32+(lane>>4)*8+e)*C + nt*16+(lane&15)])
//   w2s[((nt*2 +kb)*64+lane)*8+e] = bf16(w2[(kb*32+(lane>>4)*8+e)*D + nt*16+(lane&15)])
// so the GEMM kernels load B-frags as single coalesced short8 (16B/lane).
// ---------------------------------------------------------------------------
__global__ __launch_bounds__(256) void k0_pack(
    const float* __restrict__ w1, const float* __restrict__ w2,
    ushort* __restrict__ w1s, ushort* __restrict__ w2s)
{
    const int t    = blockIdx.x * 256 + threadIdx.x;   // 0..16383
    const int lane = t & 63;
    const int hi4  = lane >> 4, lo16 = lane & 15;
    float v[8];
    ushort* dst;
    if (t < 8192) {
        const int nt = t >> 11, kb = (t >> 6) & 31;
        const float* src = w1 + (size_t)(kb * 32 + hi4 * 8) * C_ + nt * 16 + lo16;
        #pragma unroll
        for (int e = 0; e < 8; ++e) v[e] = src[e * C_];
        dst = w1s + (size_t)t * 8;
    } else {
        const int t2 = t - 8192;
        const int nt = t2 >> 7, kb = (t2 >> 6) & 1;
        const float* src = w2 + (size_t)(kb * 32 + hi4 * 8) * D_ + nt * 16 + lo16;
        #pragma unroll
        for (int e = 0; e < 8; ++e) v[e] = src[e * D_];
        dst = w2s + (size_t)t2 * 8;
    }
    *(short8*)dst = pack8(v[0], v[1], v[2], v[3], v[4], v[5], v[6], v[7]);
}

// ---------------------------------------------------------------------------
// K1: fused LayerNorm + gamma/gammax scale + GEMM1 (D->C) via bf16 MFMA.
// grid 2050, block 256 (4 waves), 32 rows/block. B-frags now come prepacked
// from w1s (one coalesced short8 per K-step instead of 8 strided loads+cvt).
// ---------------------------------------------------------------------------
__global__ __launch_bounds__(256) void k1_ln_gemm1(
    const float* __restrict__ x, const float* __restrict__ ln_w,
    const float* __restrict__ ln_b, const float* __restrict__ gamma,
    const float* __restrict__ gammax, const ushort* __restrict__ w1s,
    const float* __restrict__ b1, float* __restrict__ y1)
{
    __shared__ ushort t2[32][1024];          // bf16, swizzled, 64 KB
    const int tid  = threadIdx.x;
    const int lane = tid & 63;
    const int wv   = tid >> 6;
    const int base = blockIdx.x * 32;

    float4 lw[4], lb[4], gm[4], gx[4];
    #pragma unroll
    for (int q = 0; q < 4; ++q) {
        const int d = q * 256 + lane * 4;
        lw[q] = *(const float4*)(ln_w   + d);
        lb[q] = *(const float4*)(ln_b   + d);
        gm[q] = *(const float4*)(gamma  + d);
        gx[q] = *(const float4*)(gammax + d);
    }

    for (int j = 0; j < 8; ++j) {
        const int i = wv * 8 + j;
        const int r = base + i;
        const int b = r / N_;
        const int n = r - b * N_;
        const float* xrow = x + (size_t)n * (B_ * D_) + (size_t)b * D_;

        float4 v[4];
        float s = 0.f, sq = 0.f;
        #pragma unroll
        for (int q = 0; q < 4; ++q) {
            v[q] = *(const float4*)(xrow + q * 256 + lane * 4);
            s  += v[q].x + v[q].y + v[q].z + v[q].w;
            sq += v[q].x * v[q].x + v[q].y * v[q].y
                + v[q].z * v[q].z + v[q].w * v[q].w;
        }
        #pragma unroll
        for (int off = 32; off > 0; off >>= 1) {
            s  += __shfl_xor(s,  off, 64);
            sq += __shfl_xor(sq, off, 64);
        }
        const float mu  = s * (1.0f / D_);
        const float var = sq * (1.0f / D_) - mu * mu;
        const float rs  = rsqrtf(var + LN_EPS_F);

        char* trow = (char*)&t2[i][0];
        const int sw = (i & 7) << 4;
        #pragma unroll
        for (int q = 0; q < 4; ++q) {
            float4 o;
            o.x = ((v[q].x - mu) * rs * lw[q].x + lb[q].x) * gm[q].x + v[q].x * gx[q].x;
            o.y = ((v[q].y - mu) * rs * lw[q].y + lb[q].y) * gm[q].y + v[q].y * gx[q].y;
            o.z = ((v[q].z - mu) * rs * lw[q].z + lb[q].z) * gm[q].z + v[q].z * gx[q].z;
            o.w = ((v[q].w - mu) * rs * lw[q].w + lb[q].w) * gm[q].w + v[q].w * gx[q].w;
            unsigned int p01, p23;
            asm("v_cvt_pk_bf16_f32 %0, %1, %2" : "=v"(p01) : "v"(o.x), "v"(o.y));
            asm("v_cvt_pk_bf16_f32 %0, %1, %2" : "=v"(p23) : "v"(o.z), "v"(o.w));
            uint2v pv; pv.x = p01; pv.y = p23;
            *(uint2v*)(trow + ((q * 512 + lane * 8) ^ sw)) = pv;
        }
    }
    __syncthreads();

    const int lo16 = lane & 15;
    const int hi4  = lane >> 4;
    const int ccol = wv * 16 + lo16;
    const char* t2b  = (const char*)t2;
    const int  roff0 = lo16 * 2048;
    const int  roff1 = roff0 + 16 * 2048;
    const int  sw2   = (lo16 & 7) << 4;
    const int  hoff  = hi4 * 16;
    const short8* w1f = (const short8*)w1s + ((size_t)wv * 32) * 64 + lane;

    f32x4 acc0 = {0.f, 0.f, 0.f, 0.f};
    f32x4 acc1 = {0.f, 0.f, 0.f, 0.f};

    #pragma unroll 4
    for (int kbi = 0; kbi < 32; ++kbi) {
        const int off = (kbi * 64 + hoff) ^ sw2;
        short8 a0 = *(const short8*)(t2b + roff0 + off);
        short8 a1 = *(const short8*)(t2b + roff1 + off);
        short8 bfr = w1f[kbi * 64];
        acc0 = __builtin_amdgcn_mfma_f32_16x16x32_bf16(a0, bfr, acc0, 0, 0, 0);
        acc1 = __builtin_amdgcn_mfma_f32_16x16x32_bf16(a1, bfr, acc1, 0, 0, 0);
    }

    const float bb   = b1[ccol];
    const int   row0 = base + hi4 * 4;
    #pragma unroll
    for (int g2 = 0; g2 < 4; ++g2) {
        y1[(size_t)(row0 + g2)      * C_ + ccol] = acc0[g2] + bb;
        y1[(size_t)(row0 + 16 + g2) * C_ + ccol] = acc1[g2] + bb;
    }
}

// ---------------------------------------------------------------------------
// K2: FUSED depthwise conv (folded 7x7) + 1x1 proj (MFMA) + residuals + GELU.
// NHWC end-to-end. grid 1025: blocks 0..1023 = (b, 2-row strip); block 1024
// handles the 64 cls rows. Per block: 8 halo rows (32 px x 64 ch) in fp32 LDS
// loaded as coalesced 8KB rows; conv per-lane-channel (broadcast reads,
// wave-uniform edge branches, folded weights in 49 VGPRs); conv+identity
// packed bf16 into XOR-swizzled LDS; proj = MFMA (M=64 px, N=64, K=64);
// epilogue: +proj residual +proj_b, exact GELU, coalesced g write.
// ---------------------------------------------------------------------------
__global__ __launch_bounds__(256) void k2_conv_proj_gelu(
    const float* __restrict__ y1,
    const float* __restrict__ dw3_w, const float* __restrict__ dw3_b,
    const float* __restrict__ dw5_w, const float* __restrict__ dw5_b,
    const float* __restrict__ dw7_w, const float* __restrict__ dw7_b,
    const float* __restrict__ proj_w, const float* __restrict__ proj_b,
    float* __restrict__ g)
{
    __shared__ float  img[8 * 32 * 64];      // 64 KB: rows r0-3 .. r0+4
    __shared__ ushort sp[64 * 64];           // 8 KB: conv+identity, bf16 swizzled
    const int tid = threadIdx.x;

    if (blockIdx.x == 1024) {                // cls rows: g = gelu(y1[n=0])
        #pragma unroll
        for (int q = 0; q < 16; ++q) {
            const int t = q * 256 + tid;
            const int b = t >> 6, c = t & 63;
            const float v = y1[(size_t)b * (N_ * C_) + c];
            g[(size_t)b * (N_ * C_) + c] =
                0.5f * v * (1.0f + erff(v * 0.70710678118654752f));
        }
        return;
    }

    const int b    = blockIdx.x >> 4;
    const int st   = blockIdx.x & 15;        // strip 0..15 (2 rows each)
    const int r0   = st * 2;
    const int lane = tid & 63;
    const int wv   = tid >> 6;
    const int c    = lane;                   // channel owned by this thread

    // ---- load 8 halo rows (zero-padded), fully coalesced ----
    #pragma unroll
    for (int ri = 0; ri < 8; ++ri) {
        const int gr = r0 - 3 + ri;
        float4 a0 = {0.f, 0.f, 0.f, 0.f}, a1 = {0.f, 0.f, 0.f, 0.f};
        if ((unsigned)gr < 32u) {
            const float* src = y1 + (size_t)(b * N_ + 1 + gr * 32) * C_;
            a0 = *(const float4*)(src + tid * 8);
            a1 = *(const float4*)(src + tid * 8 + 4);
        }
        *(float4*)(img + ri * 2048 + tid * 8)     = a0;
        *(float4*)(img + ri * 2048 + tid * 8 + 4) = a1;
    }

    // ---- fold 3/5/7 kernels into one 7x7 in registers ----
    float wk[49];
    #pragma unroll
    for (int i = 0; i < 49; ++i) {
        const int di = i / 7, dj = i % 7;
        float v = dw7_w[c * 49 + i];
        if (di >= 1 && di <= 5 && dj >= 1 && dj <= 5)
            v += dw5_w[c * 25 + (di - 1) * 5 + (dj - 1)];
        if (di >= 2 && di <= 4 && dj >= 2 && dj <= 4)
            v += dw3_w[c * 9 + (di - 2) * 3 + (dj - 2)];
        wk[i] = v * (1.0f / 3.0f);
    }
    const float bias = (dw3_b[c] + dw5_b[c] + dw7_b[c]) * (1.0f / 3.0f);
    __syncthreads();

    // ---- conv: wave -> (row ro, 16-col half); lane -> channel ----
    const int ro    = wv >> 1;
    const int jbase = (wv & 1) * 16;
    char* spb = (char*)sp;
    for (int j = jbase; j < jbase + 16; ++j) {
        float acc = bias;
        #pragma unroll
        for (int ki = 0; ki < 7; ++ki) {
            const float* irow = img + (ro + ki) * 2048;   // LDS row (r0+ro+ki-3)
            #pragma unroll
            for (int kj = 0; kj < 7; ++kj) {
                const int jj = j + kj - 3;
                if ((unsigned)jj < 32u)                   // wave-uniform branch
                    acc += irow[jj * 64 + c] * wk[ki * 7 + kj];
            }
        }
        acc += img[(ro + 3) * 2048 + j * 64 + c];         // identity residual
        const int p = ro * 32 + j;                        // strip px 0..63
        unsigned u;
        asm("v_cvt_pk_bf16_f32 %0, %1, %2" : "=v"(u) : "v"(acc), "v"(acc));
        *(ushort*)(spb + p * 128 + ((c * 2) ^ ((p & 7) << 4))) = (ushort)u;
    }
    __syncthreads();

    // ---- proj via MFMA: wave wv owns out-channel tile nt=wv ----
    const int lo16 = lane & 15, hi4 = lane >> 4;
    short8 bfr[2];
    #pragma unroll
    for (int kb = 0; kb < 2; ++kb) {
        const float* pwp = proj_w + (size_t)(wv * 16 + lo16) * C_ + kb * 32 + hi4 * 8;
        bfr[kb] = pack8(pwp[0], pwp[1], pwp[2], pwp[3],
                        pwp[4], pwp[5], pwp[6], pwp[7]);
    }
    f32x4 acc[4];
    #pragma unroll
    for (int mt = 0; mt < 4; ++mt) acc[mt] = (f32x4){0.f, 0.f, 0.f, 0.f};
    #pragma unroll
    for (int mt = 0; mt < 4; ++mt) {
        #pragma unroll
        for (int kb = 0; kb < 2; ++kb) {
            const int row = mt * 16 + lo16;
            short8 af = *(const short8*)(spb + row * 128 +
                          ((kb * 64 + hi4 * 16) ^ ((row & 7) << 4)));
            acc[mt] = __builtin_amdgcn_mfma_f32_16x16x32_bf16(af, bfr[kb], acc[mt], 0, 0, 0);
        }
    }

    // ---- epilogue: sp + proj + proj_b -> GELU -> g (NHWC) ----
    const int ch  = wv * 16 + lo16;
    const float pb = proj_b[ch];
    const size_t grow0 = (size_t)(b * N_ + 1 + r0 * 32);
    #pragma unroll
    for (int mt = 0; mt < 4; ++mt) {
        #pragma unroll
        for (int g2 = 0; g2 < 4; ++g2) {
            const int px = mt * 16 + hi4 * 4 + g2;
            const ushort h = *(const ushort*)(spb + px * 128 +
                               ((ch * 2) ^ ((px & 7) << 4)));
            union { unsigned u; float f; } rb; rb.u = ((unsigned)h) << 16;
            const float o  = rb.f + acc[mt][g2] + pb;
            const float ge = 0.5f * o * (1.0f + erff(o * 0.70710678118654752f));
            g[(grow0 + px) * C_ + ch] = ge;
        }
    }
}

// ---------------------------------------------------------------------------
// K4: GEMM2 (C->D) via bf16 MFMA + b2 + identity residual + transpose store.
// grid 8200 = 2050 M-blocks x 4 N-blocks; block = 32 rows x 256 cols.
// A (g tile) staged bf16 in XOR-swizzled LDS (4 KB); B-frags are coalesced
// short8 loads from prepacked w2s (L2-resident). fp32 x/b2/accumulate.
// ---------------------------------------------------------------------------
__global__ __launch_bounds__(256) void k4_gemm2_mfma(
    const float* __restrict__ g, const ushort* __restrict__ w2s,
    const float* __restrict__ b2, const float* __restrict__ x,
    float* __restrict__ out)
{
    __shared__ ushort gs[32 * 64];           // 4 KB, swizzled bf16
    const int tid   = threadIdx.x;
    const int mb    = blockIdx.x >> 2;
    const int nb    = blockIdx.x & 3;
    const int base  = mb * 32;
    const int dbase = nb * 256;
    const int lane  = tid & 63;
    const int wv    = tid >> 6;

    // ---- stage A: 32 rows x 64 ch of g -> bf16 swizzled LDS ----
    {
        const float* src = g + (size_t)base * C_ + tid * 8;
        const float4 a0 = *(const float4*)src;
        const float4 a1 = *(const float4*)(src + 4);
        const short8 pk = pack8(a0.x, a0.y, a0.z, a0.w, a1.x, a1.y, a1.z, a1.w);
        const int row  = tid >> 3;
        const int colb = ((tid & 7) * 16) ^ ((row & 7) << 4);
        *(short8*)((char*)gs + row * 128 + colb) = pk;
    }
    __syncthreads();

    // ---- B-frags: 4 N-tiles x 2 K-blocks, coalesced from w2s ----
    short8 bfr[4][2];
    #pragma unroll
    for (int f = 0; f < 4; ++f) {
        #pragma unroll
        for (int kb = 0; kb < 2; ++kb) {
            const int nt = nb * 16 + wv * 4 + f;
            bfr[f][kb] = *(const short8*)(w2s + ((size_t)(nt * 2 + kb) * 64 + lane) * 8);
        }
    }

    const int lo16 = lane & 15, hi4 = lane >> 4;
    const char* gsb = (const char*)gs;
    f32x4 acc[2][4];
    #pragma unroll
    for (int mt = 0; mt < 2; ++mt)
        #pragma unroll
        for (int f = 0; f < 4; ++f) acc[mt][f] = (f32x4){0.f, 0.f, 0.f, 0.f};

    #pragma unroll
    for (int mt = 0; mt < 2; ++mt) {
        #pragma unroll
        for (int kb = 0; kb < 2; ++kb) {
            const int row = mt * 16 + lo16;
            short8 af = *(const short8*)(gsb + row * 128 +
                          ((kb * 64 + hi4 * 16) ^ ((row & 7) << 4)));
            #pragma unroll
            for (int f = 0; f < 4; ++f)
                acc[mt][f] = __builtin_amdgcn_mfma_f32_16x16x32_bf16(af, bfr[f][kb],
                                                                     acc[mt][f], 0, 0, 0);
        }
    }

    // ---- epilogue: + x + b2, transpose store to (N,B,D) ----
    float b2v[4];
    #pragma unroll
    for (int f = 0; f < 4; ++f) b2v[f] = b2[dbase + wv * 64 + f * 16 + lo16];

    #pragma unroll
    for (int mt = 0; mt < 2; ++mt) {
        #pragma unroll
        for (int g2 = 0; g2 < 4; ++g2) {
            const int r  = base + mt * 16 + hi4 * 4 + g2;
            const int b_ = r / N_;
            const int n_ = r - b_ * N_;
            const size_t rowoff = (size_t)n_ * (B_ * D_) + (size_t)b_ * D_;
            #pragma unroll
            for (int f = 0; f < 4; ++f) {
                const int d = dbase + wv * 64 + f * 16 + lo16;
                const float xv = x[rowoff + d];
                out[rowoff + d] = xv + acc[mt][f][g2] + b2v[f];
            }
        }
    }
}

// ---------------------------------------------------------------------------
extern "C" void kernel_launch(void* const* d_in, const int* in_sizes, int n_in,
                              void* d_out, int out_size, void* d_ws, size_t ws_size,
                              hipStream_t stream)
{
    const float* x      = (const float*)d_in[0];
    const float* ln_w   = (const float*)d_in[1];
    const float* ln_b   = (const float*)d_in[2];
    const float* gamma  = (const float*)d_in[3];
    const float* gammax = (const float*)d_in[4];
    const float* w1     = (const float*)d_in[5];
    const float* b1     = (const float*)d_in[6];
    const float* w2     = (const float*)d_in[7];
    const float* b2     = (const float*)d_in[8];
    const float* dw3_w  = (const float*)d_in[9];
    const float* dw3_b  = (const float*)d_in[10];
    const float* dw5_w  = (const float*)d_in[11];
    const float* dw5_b  = (const float*)d_in[12];
    const float* dw7_w  = (const float*)d_in[13];
    const float* dw7_b  = (const float*)d_in[14];
    const float* proj_w = (const float*)d_in[15];
    const float* proj_b = (const float*)d_in[16];
    float* out = (float*)d_out;

    // workspace: y1 (16.8 MB) | g (16.8 MB) | w1s (128 KB) | w2s (128 KB)
    float*  y1  = (float*)d_ws;
    float*  gbf = y1 + (size_t)B_ * N_ * C_;
    ushort* w1s = (ushort*)(gbf + (size_t)B_ * N_ * C_);
    ushort* w2s = w1s + 65536;

    k0_pack<<<64, 256, 0, stream>>>(w1, w2, w1s, w2s);
    k1_ln_gemm1<<<2050, 256, 0, stream>>>(x, ln_w, ln_b, gamma, gammax, w1s, b1, y1);
    k2_conv_proj_gelu<<<1025, 256, 0, stream>>>(y1, dw3_w, dw3_b, dw5_w, dw5_b,
                                                dw7_w, dw7_b, proj_w, proj_b, gbf);
    k4_gemm2_mfma<<<8200, 256, 0, stream>>>(gbf, w2s, b2, x, out);
}